// Round 7
// baseline (205.520 us; speedup 1.0000x reference)
//
#include <hip/hip_runtime.h>

#define BATCH 8192
#define DIM 1024
#define HEADS 8
#define HEAD_DIM 128
#define DSTATE 256

typedef __attribute__((ext_vector_type(8))) short short8v;   // 8 bf16 (4 VGPRs)
typedef __attribute__((ext_vector_type(4))) float f32x4;
typedef __attribute__((ext_vector_type(4))) unsigned short ushort4v;
typedef __attribute__((ext_vector_type(4))) unsigned int uint4v;

__device__ __forceinline__ unsigned short f2bf(float x) {
  unsigned int u = __builtin_bit_cast(unsigned int, x);
  unsigned int r = u + 0x7FFFu + ((u >> 16) & 1u);   // RNE
  return (unsigned short)(r >> 16);
}
__device__ __forceinline__ float bf2f(unsigned short h) {
  unsigned int u = ((unsigned int)h) << 16;
  return __builtin_bit_cast(float, u);
}

// Row permutation (within each head): stored row s <-> true n.
//   s = 32j + 16t + 4g + r   <->   n = 32j + 8g + 4t + r
// GEMM1's MFMA output (rows s) then lands exactly in GEMM2's B-operand layout.

// ---------- precompute: A_bar (PERMUTED layout) and coef=(A_bar-1)/A (natural) ----------
__global__ void pc_params(const float* __restrict__ logdt,
                          const float* __restrict__ arelog,
                          const float* __restrict__ aim,
                          float* __restrict__ abr, float* __restrict__ abi,
                          float* __restrict__ cre, float* __restrict__ cim) {
  int i = blockIdx.x * 256 + threadIdx.x;            // i = h*256 + n (natural)
  float ld = logdt[i];
  float dt = log1pf(expf(ld));                       // softplus
  float Ar = -expf(arelog[i]);
  float Ai = aim[i];
  float e  = expf(dt * Ar);
  float th = dt * Ai;
  float Abr = e * cosf(th), Abi = e * sinf(th);
  int n = i & 255, h = i >> 8;
  // inverse permutation: n -> s
  int s = (n & ~31) + ((n >> 2) & 1) * 16 + ((n >> 3) & 3) * 4 + (n & 3);
  abr[h * 256 + s] = Abr; abi[h * 256 + s] = Abi;
  float den = Ar * Ar + Ai * Ai;
  float br = Abr - 1.0f;
  cre[i] = (br * Ar + Abi * Ai) / den;
  cim[i] = (Abi * Ar - br * Ai) / den;
}

// ---------- W1 = coef * B  (bf16, PERMUTED rows, layout (H, s, P)) ----------
__global__ void pc_w1(const float* __restrict__ Bre, const float* __restrict__ Bim,
                      const float* __restrict__ cre, const float* __restrict__ cim,
                      unsigned short* __restrict__ w1re, unsigned short* __restrict__ w1im) {
  int i = blockIdx.x * 256 + threadIdx.x;            // stored flat idx: h*32768 + s*128 + p
  int p = i & 127, s = (i >> 7) & 255, h = i >> 15;
  int kk = s >> 4, u = s & 15;
  int n = ((kk >> 1) << 5) + ((u >> 2) & 3) * 8 + (kk & 1) * 4 + (u & 3);
  int src = (h * 256 + n) * 128 + p;
  int hn = h * 256 + n;
  float cr = cre[hn], ci = cim[hn];
  float br = Bre[src], bi = Bim[src];
  w1re[i] = f2bf(cr * br - ci * bi);
  w1im[i] = f2bf(cr * bi + ci * br);
}

// ---------- W2 = C_re, -C_im  (bf16, natural layout (H,P,N)) ----------
__global__ void pc_w2(const float* __restrict__ Cre, const float* __restrict__ Cim,
                      unsigned short* __restrict__ w2re, unsigned short* __restrict__ w2mi) {
  int i = blockIdx.x * 256 + threadIdx.x;            // 262144 = H*P*N
  w2re[i] = f2bf(Cre[i]);
  w2mi[i] = f2bf(-Cim[i]);
}

// ---------- RMSNorm -> x_hat bf16 (one wave per row) ----------
__global__ __launch_bounds__(256) void rms_k(const float* __restrict__ xt,
                                             const float* __restrict__ w,
                                             unsigned short* __restrict__ xbf) {
  int wid = threadIdx.x >> 6, lane = threadIdx.x & 63;
  int row = blockIdx.x * 4 + wid;
  const float* xr = xt + (long)row * DIM;
  f32x4 v[4];
  float ssq = 0.f;
  #pragma unroll
  for (int c = 0; c < 4; ++c) {
    v[c] = *(const f32x4*)(xr + c * 256 + lane * 4);
    ssq += v[c][0]*v[c][0] + v[c][1]*v[c][1] + v[c][2]*v[c][2] + v[c][3]*v[c][3];
  }
  #pragma unroll
  for (int m = 1; m < 64; m <<= 1) ssq += __shfl_xor(ssq, m, 64);
  float sc = rsqrtf(ssq * (1.0f / DIM) + 1e-4f);
  unsigned short* orow = xbf + (long)row * DIM;
  #pragma unroll
  for (int c = 0; c < 4; ++c) {
    f32x4 w4 = *(const f32x4*)(w + c * 256 + lane * 4);
    ushort4v o;
    o[0] = f2bf(v[c][0] * sc * w4[0]);
    o[1] = f2bf(v[c][1] * sc * w4[1]);
    o[2] = f2bf(v[c][2] * sc * w4[2]);
    o[3] = f2bf(v[c][3] * sc * w4[3]);
    *(ushort4v*)(orow + c * 256 + lane * 4) = o;
  }
}

// ---------- main fused kernel: n-split waves, preloaded state, clean stores ----------
// Grid: 4096 blocks = 512 row-tiles x 8 heads, 256 threads = 4 waves.
// Wave wn: 16 batch rows x n-quarter [64*wn, 64*wn+64) (windows j = 2wn, 2wn+1).
// GEMM1 (permuted W1) -> recurrence -> shfl-fixed CONTIGUOUS ns stores ->
// partial GEMM2 (K=64). Partial Ch reduced across waves via 24KB LDS + 1 barrier;
// wave 0 does the epilogue. All state preloaded at wave start (16-deep MLP).
__global__ __launch_bounds__(256, 3) void s5_main(
    const unsigned short* __restrict__ xbf,
    const unsigned short* __restrict__ w1re, const unsigned short* __restrict__ w1im,
    const unsigned short* __restrict__ w2re, const unsigned short* __restrict__ w2mi,
    const float* __restrict__ abrp, const float* __restrict__ abip,
    const float* __restrict__ sre, const float* __restrict__ sim,
    const float* __restrict__ xt, const float* __restrict__ dvec,
    float* __restrict__ out, float* __restrict__ nsre, float* __restrict__ nsim) {
  __shared__ float reduc[3][8][64][4];               // 24 KB
  const int tid = threadIdx.x;
  const int wn = tid >> 6, lane = tid & 63;
  const int g = lane >> 4, bl = lane & 15;
  const int h = blockIdx.x & 7;
  const int b = (blockIdx.x >> 3) * 16 + bl;
  const int j0 = wn * 2;

  // x_hat B-fragments (GEMM1): lane (g,bl): col b, k = p = ks*32 + g*8 + e
  short8v xf[4];
  {
    const unsigned short* xrow = xbf + (size_t)b * DIM + h * HEAD_DIM + g * 8;
    #pragma unroll
    for (int ks = 0; ks < 4; ++ks)
      xf[ks] = *(const short8v*)(xrow + ks * 32);
  }

  // preload ALL of this wave's state (2 windows x 2 t-halves, re+im)
  const size_t sbase = ((size_t)b * HEADS + h) * DSTATE;
  f32x4 sR[2][2], sI[2][2];
  #pragma unroll
  for (int w2 = 0; w2 < 2; ++w2) {
    #pragma unroll
    for (int t = 0; t < 2; ++t) {
      const int no = (j0 + w2) * 32 + g * 8 + t * 4;
      sR[w2][t] = *(const f32x4*)(sre + sbase + no);
      sI[w2][t] = *(const f32x4*)(sim + sbase + no);
    }
  }

  f32x4 acc[8];
  #pragma unroll
  for (int pt = 0; pt < 8; ++pt) { f32x4 z = {0.f,0.f,0.f,0.f}; acc[pt] = z; }

  const int srcA = ((g >> 1) << 4) + bl;             // shfl sources for store fix-up
  const int srcB = (((g >> 1) + 2) << 4) + bl;

  #pragma unroll
  for (int w2 = 0; w2 < 2; ++w2) {
    const int j = j0 + w2;
    f32x4 nre[2], nim[2];
    unsigned pr0 = 0, pr1 = 0, pi0 = 0, pi1 = 0;
    short8v pbr, pbi;
    #pragma unroll
    for (int t = 0; t < 2; ++t) {
      const int kk = 2 * j + t;
      const unsigned short* w1b = w1re + ((size_t)(h * DSTATE + kk * 16 + bl)) * HEAD_DIM + g * 8;
      const unsigned short* w1c = w1im + ((size_t)(h * DSTATE + kk * 16 + bl)) * HEAD_DIM + g * 8;
      f32x4 dr = {0.f,0.f,0.f,0.f};
      f32x4 di = {0.f,0.f,0.f,0.f};
      #pragma unroll
      for (int ks = 0; ks < 4; ++ks) {
        short8v ar = *(const short8v*)(w1b + ks * 32);
        dr = __builtin_amdgcn_mfma_f32_16x16x32_bf16(ar, xf[ks], dr, 0, 0, 0);
      }
      #pragma unroll
      for (int ks = 0; ks < 4; ++ks) {
        short8v ai = *(const short8v*)(w1c + ks * 32);
        di = __builtin_amdgcn_mfma_f32_16x16x32_bf16(ai, xf[ks], di, 0, 0, 0);
      }
      const f32x4 Ar = *(const f32x4*)(abrp + h * DSTATE + kk * 16 + g * 4);
      const f32x4 Ai = *(const f32x4*)(abip + h * DSTATE + kk * 16 + g * 4);
      f32x4 nr, ni;
      #pragma unroll
      for (int r = 0; r < 4; ++r) {
        nr[r] = fmaf(Ar[r], sR[w2][t][r], fmaf(-Ai[r], sI[w2][t][r], dr[r]));
        ni[r] = fmaf(Ar[r], sI[w2][t][r], fmaf(Ai[r], sR[w2][t][r], di[r]));
      }
      nre[t] = nr; nim[t] = ni;
      unsigned lo  = (unsigned)f2bf(nr[0]) | ((unsigned)f2bf(nr[1]) << 16);
      unsigned hi  = (unsigned)f2bf(nr[2]) | ((unsigned)f2bf(nr[3]) << 16);
      unsigned lo2 = (unsigned)f2bf(ni[0]) | ((unsigned)f2bf(ni[1]) << 16);
      unsigned hi2 = (unsigned)f2bf(ni[2]) | ((unsigned)f2bf(ni[3]) << 16);
      if (t == 0) {
        pr0 = lo; pr1 = hi; pi0 = lo2; pi1 = hi2;
      } else {
        uint4v urv; urv[0] = pr0; urv[1] = pr1; urv[2] = lo;  urv[3] = hi;
        uint4v uiv; uiv[0] = pi0; uiv[1] = pi1; uiv[2] = lo2; uiv[3] = hi2;
        pbr = __builtin_bit_cast(short8v, urv);
        pbi = __builtin_bit_cast(short8v, uiv);
      }
    }

    // shfl fix-up -> per-instruction g-quad-contiguous ns stores (no write amp)
    {
      f32x4 v1r, v2r, v1i, v2i;
      #pragma unroll
      for (int e = 0; e < 4; ++e) {
        float a1 = __shfl(nre[0][e], srcA, 64);
        float b1 = __shfl(nre[1][e], srcA, 64);
        v1r[e] = (g & 1) ? b1 : a1;
        float a2 = __shfl(nre[0][e], srcB, 64);
        float b2 = __shfl(nre[1][e], srcB, 64);
        v2r[e] = (g & 1) ? b2 : a2;
        float c1 = __shfl(nim[0][e], srcA, 64);
        float d1 = __shfl(nim[1][e], srcA, 64);
        v1i[e] = (g & 1) ? d1 : c1;
        float c2 = __shfl(nim[0][e], srcB, 64);
        float d2 = __shfl(nim[1][e], srcB, 64);
        v2i[e] = (g & 1) ? d2 : c2;
      }
      const size_t no = sbase + j * 32 + g * 4;
      *(f32x4*)(nsre + no)      = v1r;
      *(f32x4*)(nsre + no + 16) = v2r;
      *(f32x4*)(nsim + no)      = v1i;
      *(f32x4*)(nsim + no + 16) = v2i;
    }

    // partial GEMM2 over this 32-state window
    const unsigned short* w2rb = w2re + ((size_t)(h * HEAD_DIM + bl)) * DSTATE + j * 32 + g * 8;
    const unsigned short* w2ib = w2mi + ((size_t)(h * HEAD_DIM + bl)) * DSTATE + j * 32 + g * 8;
    #pragma unroll
    for (int pt = 0; pt < 8; ++pt) {
      short8v a2r = *(const short8v*)(w2rb + pt * 16 * DSTATE);
      short8v a2i = *(const short8v*)(w2ib + pt * 16 * DSTATE);
      acc[pt] = __builtin_amdgcn_mfma_f32_16x16x32_bf16(a2r, pbr, acc[pt], 0, 0, 0);
      acc[pt] = __builtin_amdgcn_mfma_f32_16x16x32_bf16(a2i, pbi, acc[pt], 0, 0, 0);
    }
  }

  // cross-wave reduction of partial Ch
  if (wn > 0) {
    #pragma unroll
    for (int pt = 0; pt < 8; ++pt)
      *(f32x4*)&reduc[wn - 1][pt][lane][0] = acc[pt];
  }
  __syncthreads();
  if (wn == 0) {
    #pragma unroll
    for (int pt = 0; pt < 8; ++pt) {
      f32x4 a = acc[pt];
      #pragma unroll
      for (int wv = 0; wv < 3; ++wv) {
        f32x4 p = *(const f32x4*)&reduc[wv][pt][lane][0];
        a[0] += p[0]; a[1] += p[1]; a[2] += p[2]; a[3] += p[3];
      }
      const int col = h * HEAD_DIM + pt * 16 + g * 4;
      const size_t o = (size_t)b * DIM + col;
      const f32x4 xt4 = *(const f32x4*)(xt + o);
      const f32x4 d4 = *(const f32x4*)(dvec + col);
      ushort4v xh4 = *(const ushort4v*)(xbf + o);
      f32x4 ro;
      #pragma unroll
      for (int r = 0; r < 4; ++r)
        ro[r] = xt4[r] + 2.0f * a[r] + d4[r] * bf2f(xh4[r]);
      *(f32x4*)(out + o) = ro;
    }
  }
}

extern "C" void kernel_launch(void* const* d_in, const int* in_sizes, int n_in,
                              void* d_out, int out_size, void* d_ws, size_t ws_size,
                              hipStream_t stream) {
  const float* x_t      = (const float*)d_in[0];
  const float* state_re = (const float*)d_in[1];
  const float* state_im = (const float*)d_in[2];
  const float* norm_w   = (const float*)d_in[3];
  const float* A_re_log = (const float*)d_in[4];
  const float* A_im     = (const float*)d_in[5];
  const float* B_re     = (const float*)d_in[6];
  const float* B_im     = (const float*)d_in[7];
  const float* C_re     = (const float*)d_in[8];
  const float* C_im     = (const float*)d_in[9];
  const float* Dv       = (const float*)d_in[10];
  const float* log_dt   = (const float*)d_in[11];

  float* out   = (float*)d_out;
  float* ns_re = out + (size_t)BATCH * DIM;
  float* ns_im = ns_re + (size_t)BATCH * HEADS * DSTATE;

  char* ws = (char*)d_ws;
  unsigned short* xbf  = (unsigned short*)ws;                       // 16 MB
  unsigned short* w1re = (unsigned short*)(ws + 16777216);          // 512 KB each
  unsigned short* w1im = w1re + 262144;
  unsigned short* w2re = w1im + 262144;
  unsigned short* w2mi = w2re + 262144;
  float* abr = (float*)(ws + 16777216 + 4 * 524288);
  float* abi = abr + 2048;
  float* cre = abi + 2048;
  float* cim = cre + 2048;

  pc_params<<<8, 256, 0, stream>>>(log_dt, A_re_log, A_im, abr, abi, cre, cim);
  pc_w1<<<1024, 256, 0, stream>>>(B_re, B_im, cre, cim, w1re, w1im);
  pc_w2<<<1024, 256, 0, stream>>>(C_re, C_im, w2re, w2mi);
  rms_k<<<2048, 256, 0, stream>>>(x_t, norm_w, xbf);
  s5_main<<<4096, 256, 0, stream>>>(xbf, w1re, w1im, w2re, w2mi, abr, abi,
                                    state_re, state_im, x_t, Dv, out, ns_re, ns_im);
}

// Round 8
// 181.094 us; speedup vs baseline: 1.1349x; 1.1349x over previous
//
#include <hip/hip_runtime.h>

#define BATCH 8192
#define DIM 1024
#define HEADS 8
#define HEAD_DIM 128
#define DSTATE 256

typedef __attribute__((ext_vector_type(8))) short short8v;   // 8 bf16 (4 VGPRs)
typedef __attribute__((ext_vector_type(4))) float f32x4;
typedef __attribute__((ext_vector_type(4))) unsigned short ushort4v;
typedef __attribute__((ext_vector_type(4))) unsigned int uint4v;

__device__ __forceinline__ unsigned short f2bf(float x) {
  unsigned int u = __builtin_bit_cast(unsigned int, x);
  unsigned int r = u + 0x7FFFu + ((u >> 16) & 1u);   // RNE
  return (unsigned short)(r >> 16);
}
__device__ __forceinline__ float bf2f(unsigned short h) {
  unsigned int u = ((unsigned int)h) << 16;
  return __builtin_bit_cast(float, u);
}

// async global->LDS, 16B per lane: LDS dest = uniform base + lane*16,
// global source is PER-LANE (lets us pre-swizzle the source).
__device__ __forceinline__ void stage16(const float* g, float* l) {
  __builtin_amdgcn_global_load_lds(
      (const __attribute__((address_space(1))) unsigned int*)g,
      (__attribute__((address_space(3))) unsigned int*)l, 16, 0, 0);
}

// Row permutation (within each head): stored row s <-> true n.
//   s = 32j + 16t + 4g + r   <->   n = 32j + 8g + 4t + r
// GEMM1's MFMA output (rows s) then lands exactly in GEMM2's B-operand layout.

// ---------- precompute: A_bar (PERMUTED layout) and coef=(A_bar-1)/A ----------
__global__ void pc_params(const float* __restrict__ logdt,
                          const float* __restrict__ arelog,
                          const float* __restrict__ aim,
                          float* __restrict__ abr, float* __restrict__ abi,
                          float* __restrict__ cre, float* __restrict__ cim) {
  int i = blockIdx.x * 256 + threadIdx.x;            // i = h*256 + n (natural)
  float ld = logdt[i];
  float dt = log1pf(expf(ld));                       // softplus
  float Ar = -expf(arelog[i]);
  float Ai = aim[i];
  float e  = expf(dt * Ar);
  float th = dt * Ai;
  float Abr = e * cosf(th), Abi = e * sinf(th);
  int n = i & 255, h = i >> 8;
  // inverse permutation: n -> s
  int s = (n & ~31) + ((n >> 2) & 1) * 16 + ((n >> 3) & 3) * 4 + (n & 3);
  abr[h * 256 + s] = Abr; abi[h * 256 + s] = Abi;
  float den = Ar * Ar + Ai * Ai;
  float br = Abr - 1.0f;
  cre[i] = (br * Ar + Abi * Ai) / den;
  cim[i] = (Abi * Ar - br * Ai) / den;
}

// ---------- W1 = coef * B  (bf16, PERMUTED rows, layout (H, s, P)) ----------
__global__ void pc_w1(const float* __restrict__ Bre, const float* __restrict__ Bim,
                      const float* __restrict__ cre, const float* __restrict__ cim,
                      unsigned short* __restrict__ w1re, unsigned short* __restrict__ w1im) {
  int i = blockIdx.x * 256 + threadIdx.x;            // h*32768 + s*128 + p
  int p = i & 127, s = (i >> 7) & 255, h = i >> 15;
  int kk = s >> 4, u = s & 15;
  int n = ((kk >> 1) << 5) + ((u >> 2) & 3) * 8 + (kk & 1) * 4 + (u & 3);
  int src = (h * 256 + n) * 128 + p;
  int hn = h * 256 + n;
  float cr = cre[hn], ci = cim[hn];
  float br = Bre[src], bi = Bim[src];
  w1re[i] = f2bf(cr * br - ci * bi);
  w1im[i] = f2bf(cr * bi + ci * br);
}

// ---------- W2 = C_re, -C_im  (bf16, natural layout (H,P,N)) ----------
__global__ void pc_w2(const float* __restrict__ Cre, const float* __restrict__ Cim,
                      unsigned short* __restrict__ w2re, unsigned short* __restrict__ w2mi) {
  int i = blockIdx.x * 256 + threadIdx.x;            // 262144 = H*P*N
  w2re[i] = f2bf(Cre[i]);
  w2mi[i] = f2bf(-Cim[i]);
}

// ---------- RMSNorm -> x_hat bf16 (one wave per row) ----------
__global__ __launch_bounds__(256) void rms_k(const float* __restrict__ xt,
                                             const float* __restrict__ w,
                                             unsigned short* __restrict__ xbf) {
  int wid = threadIdx.x >> 6, lane = threadIdx.x & 63;
  int row = blockIdx.x * 4 + wid;
  const float* xr = xt + (long)row * DIM;
  f32x4 v[4];
  float ssq = 0.f;
  #pragma unroll
  for (int c = 0; c < 4; ++c) {
    v[c] = *(const f32x4*)(xr + c * 256 + lane * 4);
    ssq += v[c][0]*v[c][0] + v[c][1]*v[c][1] + v[c][2]*v[c][2] + v[c][3]*v[c][3];
  }
  #pragma unroll
  for (int m = 1; m < 64; m <<= 1) ssq += __shfl_xor(ssq, m, 64);
  float sc = rsqrtf(ssq * (1.0f / DIM) + 1e-4f);
  unsigned short* orow = xbf + (long)row * DIM;
  #pragma unroll
  for (int c = 0; c < 4; ++c) {
    f32x4 w4 = *(const f32x4*)(w + c * 256 + lane * 4);
    ushort4v o;
    o[0] = f2bf(v[c][0] * sc * w4[0]);
    o[1] = f2bf(v[c][1] * sc * w4[1]);
    o[2] = f2bf(v[c][2] * sc * w4[2]);
    o[3] = f2bf(v[c][3] * sc * w4[3]);
    *(ushort4v*)(orow + c * 256 + lane * 4) = o;
  }
}

// ---------- main fused kernel: LDS-staged contiguous I/O ----------
// Grid: 4096 blocks = 512 row-tiles x 8 heads, 256 threads = 4 waves.
// Block task: 16 batch rows x 1 head.
//   Stage:   state rows -> LDS via global_load_lds (1KB contiguous per instr,
//            16B-chunk XOR swizzle applied on the per-lane GLOBAL source).
//   Phase 1: wave wn owns n-slice [64wn,64wn+64): GEMM1 (permuted W1) ->
//            recurrence (state from LDS) -> ns written back to SAME LDS slots
//            -> packed P fragments to P-LDS.
//   Phase 2: ns cooperatively stored out (1KB contiguous per instr);
//            GEMM2 p-split: wave wn owns p-rows [32wn,32wn+32) over full K=256
//            (P from LDS, W2 from L2) -> epilogue for its p-slice.
__global__ __launch_bounds__(256, 3) void s5_main(
    const unsigned short* __restrict__ xbf,
    const unsigned short* __restrict__ w1re, const unsigned short* __restrict__ w1im,
    const unsigned short* __restrict__ w2re, const unsigned short* __restrict__ w2mi,
    const float* __restrict__ abrp, const float* __restrict__ abip,
    const float* __restrict__ sre, const float* __restrict__ sim,
    const float* __restrict__ xt, const float* __restrict__ dvec,
    float* __restrict__ out, float* __restrict__ nsre, float* __restrict__ nsim) {
  __shared__ float Sst[2][16][256];                  // 32 KB state->ns tile
  __shared__ unsigned short pfrag[2][8][64][8];      // 16 KB P exchange
  const int tid = threadIdx.x;
  const int wn = tid >> 6, lane = tid & 63;
  const int g = lane >> 4, bl = lane & 15;
  const int h = blockIdx.x & 7;
  const int rowbase = (blockIdx.x >> 3) * 16;

  // ---- stage-in: wave wn stages rows 4wn..4wn+3, both components ----
  #pragma unroll
  for (int i = 0; i < 4; ++i) {
    const int row = wn * 4 + i;
    const size_t rb = ((size_t)(rowbase + row) * HEADS + h) * DSTATE;
    const int sc = (lane ^ (row & 7)) * 4;           // pre-swizzled source chunk
    stage16(sre + rb + sc, &Sst[0][row][0]);
    stage16(sim + rb + sc, &Sst[1][row][0]);
  }

  // x_hat B-fragments (GEMM1), direct from global (L2/L3-resident)
  short8v xf[4];
  {
    const unsigned short* xrow = xbf + (size_t)(rowbase + bl) * DIM + h * HEAD_DIM + g * 8;
    #pragma unroll
    for (int ks = 0; ks < 4; ++ks)
      xf[ks] = *(const short8v*)(xrow + ks * 32);
  }

  __syncthreads();                                    // stage data landed

  // ---- phase 1: GEMM1 + recurrence on n-slice [64wn, 64wn+64) ----
  #pragma unroll
  for (int w2 = 0; w2 < 2; ++w2) {
    const int j = 2 * wn + w2;
    unsigned pr0 = 0, pr1 = 0, pi0 = 0, pi1 = 0;
    #pragma unroll
    for (int t = 0; t < 2; ++t) {
      const int kk = 2 * j + t;
      const unsigned short* w1b = w1re + ((size_t)(h * DSTATE + kk * 16 + bl)) * HEAD_DIM + g * 8;
      const unsigned short* w1c = w1im + ((size_t)(h * DSTATE + kk * 16 + bl)) * HEAD_DIM + g * 8;
      f32x4 dr = {0.f,0.f,0.f,0.f};
      f32x4 di = {0.f,0.f,0.f,0.f};
      #pragma unroll
      for (int ks = 0; ks < 4; ++ks) {
        short8v ar = *(const short8v*)(w1b + ks * 32);
        dr = __builtin_amdgcn_mfma_f32_16x16x32_bf16(ar, xf[ks], dr, 0, 0, 0);
      }
      #pragma unroll
      for (int ks = 0; ks < 4; ++ks) {
        short8v ai = *(const short8v*)(w1c + ks * 32);
        di = __builtin_amdgcn_mfma_f32_16x16x32_bf16(ai, xf[ks], di, 0, 0, 0);
      }
      // state from LDS (swizzled chunk), recurrence, ns back to same slots
      const int c = (((8 * j + 2 * g + t) ^ (bl & 7)) << 2);
      const f32x4 s_r = *(const f32x4*)&Sst[0][bl][c];
      const f32x4 s_i = *(const f32x4*)&Sst[1][bl][c];
      const f32x4 Ar = *(const f32x4*)(abrp + h * DSTATE + kk * 16 + g * 4);
      const f32x4 Ai = *(const f32x4*)(abip + h * DSTATE + kk * 16 + g * 4);
      f32x4 nr, ni;
      #pragma unroll
      for (int r = 0; r < 4; ++r) {
        nr[r] = fmaf(Ar[r], s_r[r], fmaf(-Ai[r], s_i[r], dr[r]));
        ni[r] = fmaf(Ar[r], s_i[r], fmaf(Ai[r], s_r[r], di[r]));
      }
      *(f32x4*)&Sst[0][bl][c] = nr;
      *(f32x4*)&Sst[1][bl][c] = ni;
      unsigned lo  = (unsigned)f2bf(nr[0]) | ((unsigned)f2bf(nr[1]) << 16);
      unsigned hi  = (unsigned)f2bf(nr[2]) | ((unsigned)f2bf(nr[3]) << 16);
      unsigned lo2 = (unsigned)f2bf(ni[0]) | ((unsigned)f2bf(ni[1]) << 16);
      unsigned hi2 = (unsigned)f2bf(ni[2]) | ((unsigned)f2bf(ni[3]) << 16);
      if (t == 0) { pr0 = lo; pr1 = hi; pi0 = lo2; pi1 = hi2; }
      else {
        uint4v urv; urv[0] = pr0; urv[1] = pr1; urv[2] = lo;  urv[3] = hi;
        uint4v uiv; uiv[0] = pi0; uiv[1] = pi1; uiv[2] = lo2; uiv[3] = hi2;
        *(short8v*)&pfrag[0][j][lane][0] = __builtin_bit_cast(short8v, urv);
        *(short8v*)&pfrag[1][j][lane][0] = __builtin_bit_cast(short8v, uiv);
      }
    }
  }

  __syncthreads();                                    // ns + P complete

  // ---- phase 2a: cooperative contiguous ns store-out ----
  #pragma unroll
  for (int i = 0; i < 4; ++i) {
    const int row = wn * 4 + i;
    const size_t rb = ((size_t)(rowbase + row) * HEADS + h) * DSTATE;
    const int gc = (lane ^ (row & 7)) * 4;            // de-swizzled global chunk
    const f32x4 vr = *(const f32x4*)&Sst[0][row][lane * 4];
    const f32x4 vi = *(const f32x4*)&Sst[1][row][lane * 4];
    *(f32x4*)(nsre + rb + gc) = vr;
    *(f32x4*)(nsim + rb + gc) = vi;
  }

  // ---- phase 2b: GEMM2, p-split: wave wn owns p-rows [32wn, 32wn+32) ----
  f32x4 a2[2];
  { f32x4 z = {0.f,0.f,0.f,0.f}; a2[0] = z; a2[1] = z; }
  #pragma unroll
  for (int j = 0; j < 8; ++j) {
    const short8v pbr = *(const short8v*)&pfrag[0][j][lane][0];
    const short8v pbi = *(const short8v*)&pfrag[1][j][lane][0];
    #pragma unroll
    for (int w2 = 0; w2 < 2; ++w2) {
      const int pt = 2 * wn + w2;
      const unsigned short* w2rb = w2re + ((size_t)(h * HEAD_DIM + pt * 16 + bl)) * DSTATE + j * 32 + g * 8;
      const unsigned short* w2ib = w2mi + ((size_t)(h * HEAD_DIM + pt * 16 + bl)) * DSTATE + j * 32 + g * 8;
      const short8v a2r = *(const short8v*)w2rb;
      const short8v a2i = *(const short8v*)w2ib;
      a2[w2] = __builtin_amdgcn_mfma_f32_16x16x32_bf16(a2r, pbr, a2[w2], 0, 0, 0);
      a2[w2] = __builtin_amdgcn_mfma_f32_16x16x32_bf16(a2i, pbi, a2[w2], 0, 0, 0);
    }
  }

  // ---- epilogue: out = x_t + 2*Ch + D*x_hat for p-slice ----
  #pragma unroll
  for (int w2 = 0; w2 < 2; ++w2) {
    const int pt = 2 * wn + w2;
    const int col = h * HEAD_DIM + pt * 16 + g * 4;
    const size_t o = (size_t)(rowbase + bl) * DIM + col;
    const f32x4 xt4 = *(const f32x4*)(xt + o);
    const f32x4 d4 = *(const f32x4*)(dvec + col);
    const ushort4v xh4 = *(const ushort4v*)(xbf + o);
    f32x4 ro;
    #pragma unroll
    for (int r = 0; r < 4; ++r)
      ro[r] = xt4[r] + 2.0f * a2[w2][r] + d4[r] * bf2f(xh4[r]);
    *(f32x4*)(out + o) = ro;
  }
}

extern "C" void kernel_launch(void* const* d_in, const int* in_sizes, int n_in,
                              void* d_out, int out_size, void* d_ws, size_t ws_size,
                              hipStream_t stream) {
  const float* x_t      = (const float*)d_in[0];
  const float* state_re = (const float*)d_in[1];
  const float* state_im = (const float*)d_in[2];
  const float* norm_w   = (const float*)d_in[3];
  const float* A_re_log = (const float*)d_in[4];
  const float* A_im     = (const float*)d_in[5];
  const float* B_re     = (const float*)d_in[6];
  const float* B_im     = (const float*)d_in[7];
  const float* C_re     = (const float*)d_in[8];
  const float* C_im     = (const float*)d_in[9];
  const float* Dv       = (const float*)d_in[10];
  const float* log_dt   = (const float*)d_in[11];

  float* out   = (float*)d_out;
  float* ns_re = out + (size_t)BATCH * DIM;
  float* ns_im = ns_re + (size_t)BATCH * HEADS * DSTATE;

  char* ws = (char*)d_ws;
  unsigned short* xbf  = (unsigned short*)ws;                       // 16 MB
  unsigned short* w1re = (unsigned short*)(ws + 16777216);          // 512 KB each
  unsigned short* w1im = w1re + 262144;
  unsigned short* w2re = w1im + 262144;
  unsigned short* w2mi = w2re + 262144;
  float* abr = (float*)(ws + 16777216 + 4 * 524288);
  float* abi = abr + 2048;
  float* cre = abi + 2048;
  float* cim = cre + 2048;

  pc_params<<<8, 256, 0, stream>>>(log_dt, A_re_log, A_im, abr, abi, cre, cim);
  pc_w1<<<1024, 256, 0, stream>>>(B_re, B_im, cre, cim, w1re, w1im);
  pc_w2<<<1024, 256, 0, stream>>>(C_re, C_im, w2re, w2mi);
  rms_k<<<2048, 256, 0, stream>>>(x_t, norm_w, xbf);
  s5_main<<<4096, 256, 0, stream>>>(xbf, w1re, w1im, w2re, w2mi, abr, abi,
                                    state_re, state_im, x_t, Dv, out, ns_re, ns_im);
}

// Round 9
// 101.080 us; speedup vs baseline: 2.0333x; 1.7916x over previous
//
#include <hip/hip_runtime.h>

#define BATCH 8192
#define DIM 1024
#define HEADS 8
#define HEAD_DIM 128
#define DSTATE 256

typedef __attribute__((ext_vector_type(8))) short short8v;   // 8 bf16 (4 VGPRs)
typedef __attribute__((ext_vector_type(4))) float f32x4;
typedef __attribute__((ext_vector_type(4))) unsigned short ushort4v;
typedef __attribute__((ext_vector_type(4))) unsigned int uint4v;

__device__ __forceinline__ unsigned short f2bf(float x) {
  unsigned int u = __builtin_bit_cast(unsigned int, x);
  unsigned int r = u + 0x7FFFu + ((u >> 16) & 1u);   // RNE
  return (unsigned short)(r >> 16);
}
__device__ __forceinline__ float bf2f(unsigned short h) {
  unsigned int u = ((unsigned int)h) << 16;
  return __builtin_bit_cast(float, u);
}

// async global->LDS: dest = uniform LDS base + lane*16; source is PER-LANE.
__device__ __forceinline__ void stage16f(const float* g, float* l) {
  __builtin_amdgcn_global_load_lds(
      (const __attribute__((address_space(1))) unsigned int*)g,
      (__attribute__((address_space(3))) unsigned int*)l, 16, 0, 0);
}
__device__ __forceinline__ void stage16u(const unsigned short* g, unsigned short* l) {
  __builtin_amdgcn_global_load_lds(
      (const __attribute__((address_space(1))) unsigned int*)g,
      (__attribute__((address_space(3))) unsigned int*)l, 16, 0, 0);
}

#define BARRIER() do { \
  asm volatile("s_waitcnt lgkmcnt(0)" ::: "memory"); \
  __builtin_amdgcn_s_barrier(); \
  asm volatile("" ::: "memory"); } while (0)

// Row permutation (within each head): stored row s <-> true n.
//   s = 32j + 16t + 4g + r   <->   n = 32j + 8g + 4t + r
// GEMM1's MFMA output (rows s) lands exactly in GEMM2's B-operand layout.

// ---------- precompute: A_bar (PERMUTED layout) and coef=(A_bar-1)/A ----------
__global__ void pc_params(const float* __restrict__ logdt,
                          const float* __restrict__ arelog,
                          const float* __restrict__ aim,
                          float* __restrict__ abr, float* __restrict__ abi,
                          float* __restrict__ cre, float* __restrict__ cim) {
  int i = blockIdx.x * 256 + threadIdx.x;            // i = h*256 + n (natural)
  float ld = logdt[i];
  float dt = log1pf(expf(ld));                       // softplus
  float Ar = -expf(arelog[i]);
  float Ai = aim[i];
  float e  = expf(dt * Ar);
  float th = dt * Ai;
  float Abr = e * cosf(th), Abi = e * sinf(th);
  int n = i & 255, h = i >> 8;
  int s = (n & ~31) + ((n >> 2) & 1) * 16 + ((n >> 3) & 3) * 4 + (n & 3);
  abr[h * 256 + s] = Abr; abi[h * 256 + s] = Abi;
  float den = Ar * Ar + Ai * Ai;
  float br = Abr - 1.0f;
  cre[i] = (br * Ar + Abi * Ai) / den;
  cim[i] = (Abi * Ar - br * Ai) / den;
}

// ---------- W1 = coef * B  (bf16, PERMUTED rows, layout (H, s, P)) ----------
__global__ void pc_w1(const float* __restrict__ Bre, const float* __restrict__ Bim,
                      const float* __restrict__ cre, const float* __restrict__ cim,
                      unsigned short* __restrict__ w1re, unsigned short* __restrict__ w1im) {
  int i = blockIdx.x * 256 + threadIdx.x;            // h*32768 + s*128 + p
  int p = i & 127, s = (i >> 7) & 255, h = i >> 15;
  int kk = s >> 4, u = s & 15;
  int n = ((kk >> 1) << 5) + ((u >> 2) & 3) * 8 + (kk & 1) * 4 + (u & 3);
  int src = (h * 256 + n) * 128 + p;
  int hn = h * 256 + n;
  float cr = cre[hn], ci = cim[hn];
  float br = Bre[src], bi = Bim[src];
  w1re[i] = f2bf(cr * br - ci * bi);
  w1im[i] = f2bf(cr * bi + ci * br);
}

// ---------- W2 = C_re, -C_im  (bf16, natural layout (H,P,N)) ----------
__global__ void pc_w2(const float* __restrict__ Cre, const float* __restrict__ Cim,
                      unsigned short* __restrict__ w2re, unsigned short* __restrict__ w2mi) {
  int i = blockIdx.x * 256 + threadIdx.x;            // 262144 = H*P*N
  w2re[i] = f2bf(Cre[i]);
  w2mi[i] = f2bf(-Cim[i]);
}

// ---------- RMSNorm -> x_hat bf16 (one wave per row) ----------
__global__ __launch_bounds__(256) void rms_k(const float* __restrict__ xt,
                                             const float* __restrict__ w,
                                             unsigned short* __restrict__ xbf) {
  int wid = threadIdx.x >> 6, lane = threadIdx.x & 63;
  int row = blockIdx.x * 4 + wid;
  const float* xr = xt + (long)row * DIM;
  f32x4 v[4];
  float ssq = 0.f;
  #pragma unroll
  for (int c = 0; c < 4; ++c) {
    v[c] = *(const f32x4*)(xr + c * 256 + lane * 4);
    ssq += v[c][0]*v[c][0] + v[c][1]*v[c][1] + v[c][2]*v[c][2] + v[c][3]*v[c][3];
  }
  #pragma unroll
  for (int m = 1; m < 64; m <<= 1) ssq += __shfl_xor(ssq, m, 64);
  float sc = rsqrtf(ssq * (1.0f / DIM) + 1e-4f);
  unsigned short* orow = xbf + (long)row * DIM;
  #pragma unroll
  for (int c = 0; c < 4; ++c) {
    f32x4 w4 = *(const f32x4*)(w + c * 256 + lane * 4);
    ushort4v o;
    o[0] = f2bf(v[c][0] * sc * w4[0]);
    o[1] = f2bf(v[c][1] * sc * w4[1]);
    o[2] = f2bf(v[c][2] * sc * w4[2]);
    o[3] = f2bf(v[c][3] * sc * w4[3]);
    *(ushort4v*)(orow + c * 256 + lane * 4) = o;
  }
}

// ---------- main: persistent block, reg weights, 3-buf counted-vmcnt pipeline ----------
// Grid: 256 blocks = 32 row-groups x 8 heads (1/CU), 512 threads = 8 waves.
// Block: 256 rows x 1 head = 16 tiles of 16 rows. Wave w: GEMM1 n-window j=w,
// GEMM2 p-tile [16w,16w+16). Per tile: stage(t+1) -> vmcnt(6) -> BAR ->
// phase1 (GEMM1+recurrence+ns->LDS+P->pf) -> BAR -> phase2 (ns out, GEMM2, out).
__global__ __launch_bounds__(512, 2) void s5_main(
    const unsigned short* __restrict__ xbf,
    const unsigned short* __restrict__ w1re, const unsigned short* __restrict__ w1im,
    const unsigned short* __restrict__ w2re, const unsigned short* __restrict__ w2mi,
    const float* __restrict__ abrp, const float* __restrict__ abip,
    const float* __restrict__ sre, const float* __restrict__ sim,
    const float* __restrict__ xt, const float* __restrict__ dvec,
    float* __restrict__ out, float* __restrict__ nsre, float* __restrict__ nsim) {
  __shared__ float Sb[3][2][16][256];                // 96 KB state/ns tiles
  __shared__ float xtl[3][16][128];                  // 24 KB x_t tiles
  __shared__ unsigned short xbl[3][16][128];         // 12 KB x_hat tiles
  __shared__ unsigned short pf[2][8][64][8];         // 16 KB P exchange
  const int tid = threadIdx.x;
  const int w = tid >> 6, lane = tid & 63;
  const int g = lane >> 4, bl = lane & 15;
  const int h = blockIdx.x & 7;
  const int blkrow = (blockIdx.x >> 3) * 256;

  // ---- persistent weights -> registers (once per block) ----
  short8v w1r[2][4], w1i[2][4];
  #pragma unroll
  for (int t = 0; t < 2; ++t) {
    const int kk = 2 * w + t;
    const unsigned short* pr = w1re + ((size_t)(h * DSTATE + kk * 16 + bl)) * HEAD_DIM + g * 8;
    const unsigned short* pi = w1im + ((size_t)(h * DSTATE + kk * 16 + bl)) * HEAD_DIM + g * 8;
    #pragma unroll
    for (int ks = 0; ks < 4; ++ks) {
      w1r[t][ks] = *(const short8v*)(pr + ks * 32);
      w1i[t][ks] = *(const short8v*)(pi + ks * 32);
    }
  }
  short8v w2r[8], w2i[8];
  {
    const unsigned short* qr = w2re + ((size_t)(h * HEAD_DIM + w * 16 + bl)) * DSTATE + g * 8;
    const unsigned short* qi = w2mi + ((size_t)(h * HEAD_DIM + w * 16 + bl)) * DSTATE + g * 8;
    #pragma unroll
    for (int j = 0; j < 8; ++j) {
      w2r[j] = *(const short8v*)(qr + j * 32);
      w2i[j] = *(const short8v*)(qi + j * 32);
    }
  }
  f32x4 Arh[2], Aih[2];
  #pragma unroll
  for (int t = 0; t < 2; ++t) {
    Arh[t] = *(const f32x4*)(abrp + h * DSTATE + (2 * w + t) * 16 + g * 4);
    Aih[t] = *(const f32x4*)(abip + h * DSTATE + (2 * w + t) * 16 + g * 4);
  }
  const f32x4 d4 = *(const f32x4*)(dvec + h * HEAD_DIM + w * 16 + g * 4);

  // ---- stage tile t into buffer b3 (per-wave: 6 instrs for w<4, else 5) ----
  auto STAGE = [&](int t, int b3) {
    const int gr0 = blkrow + t * 16;
    #pragma unroll
    for (int i = 0; i < 2; ++i) {
      const int row = 2 * w + i;
      const size_t rb = ((size_t)(gr0 + row) * HEADS + h) * DSTATE;
      const int soff = (lane ^ (row & 7)) * 4;       // pre-swizzled source chunk
      stage16f(sre + rb + soff, &Sb[b3][0][row][0]);
      stage16f(sim + rb + soff, &Sb[b3][1][row][0]);
    }
    {
      const int row = 2 * w + (lane >> 5);           // x_t: 2 rows per instr
      const float* src = xt + (size_t)(gr0 + row) * DIM + h * HEAD_DIM + (lane & 31) * 4;
      stage16f(src, &xtl[b3][2 * w][0]);
    }
    if (w < 4) {                                     // x_hat: 4 rows per instr
      const int row = 4 * w + (lane >> 4);
      const unsigned short* src = xbf + (size_t)(gr0 + row) * DIM + h * HEAD_DIM + (lane & 15) * 8;
      stage16u(src, &xbl[b3][4 * w][0]);
    }
  };

  STAGE(0, 0);
  asm volatile("s_waitcnt vmcnt(0)" ::: "memory");
  __builtin_amdgcn_s_barrier();
  asm volatile("" ::: "memory");

  int bcur = 0;
  for (int t = 0; t < 16; ++t) {
    const int bnxt = (bcur == 2) ? 0 : bcur + 1;
    if (t < 15) {
      STAGE(t + 1, bnxt);
      asm volatile("s_waitcnt vmcnt(6)" ::: "memory");
    } else {
      asm volatile("s_waitcnt vmcnt(0)" ::: "memory");
    }
    BARRIER();                                       // stage(t) visible to all

    // ---- phase 1: GEMM1 + recurrence on n-window j=w ----
    short8v xf[4];
    #pragma unroll
    for (int ks = 0; ks < 4; ++ks)
      xf[ks] = *(const short8v*)&xbl[bcur][bl][ks * 32 + g * 8];

    unsigned pr0 = 0, pr1 = 0, pi0 = 0, pi1 = 0;
    #pragma unroll
    for (int tt = 0; tt < 2; ++tt) {
      f32x4 dr = {0.f,0.f,0.f,0.f};
      f32x4 di = {0.f,0.f,0.f,0.f};
      #pragma unroll
      for (int ks = 0; ks < 4; ++ks)
        dr = __builtin_amdgcn_mfma_f32_16x16x32_bf16(w1r[tt][ks], xf[ks], dr, 0, 0, 0);
      #pragma unroll
      for (int ks = 0; ks < 4; ++ks)
        di = __builtin_amdgcn_mfma_f32_16x16x32_bf16(w1i[tt][ks], xf[ks], di, 0, 0, 0);
      const int c = (((8 * w + 2 * g + tt) ^ (bl & 7)) << 2);
      const f32x4 s_r = *(const f32x4*)&Sb[bcur][0][bl][c];
      const f32x4 s_i = *(const f32x4*)&Sb[bcur][1][bl][c];
      f32x4 nr, ni;
      #pragma unroll
      for (int r = 0; r < 4; ++r) {
        nr[r] = fmaf(Arh[tt][r], s_r[r], fmaf(-Aih[tt][r], s_i[r], dr[r]));
        ni[r] = fmaf(Arh[tt][r], s_i[r], fmaf(Aih[tt][r], s_r[r], di[r]));
      }
      *(f32x4*)&Sb[bcur][0][bl][c] = nr;
      *(f32x4*)&Sb[bcur][1][bl][c] = ni;
      unsigned lo  = (unsigned)f2bf(nr[0]) | ((unsigned)f2bf(nr[1]) << 16);
      unsigned hi  = (unsigned)f2bf(nr[2]) | ((unsigned)f2bf(nr[3]) << 16);
      unsigned lo2 = (unsigned)f2bf(ni[0]) | ((unsigned)f2bf(ni[1]) << 16);
      unsigned hi2 = (unsigned)f2bf(ni[2]) | ((unsigned)f2bf(ni[3]) << 16);
      if (tt == 0) { pr0 = lo; pr1 = hi; pi0 = lo2; pi1 = hi2; }
      else {
        uint4v urv; urv[0] = pr0; urv[1] = pr1; urv[2] = lo;  urv[3] = hi;
        uint4v uiv; uiv[0] = pi0; uiv[1] = pi1; uiv[2] = lo2; uiv[3] = hi2;
        *(short8v*)&pf[0][w][lane][0] = __builtin_bit_cast(short8v, urv);
        *(short8v*)&pf[1][w][lane][0] = __builtin_bit_cast(short8v, uiv);
      }
    }
    BARRIER();                                       // ns + P complete

    // ---- phase 2a: contiguous ns store-out (rows 2w, 2w+1) ----
    #pragma unroll
    for (int i = 0; i < 2; ++i) {
      const int row = 2 * w + i;
      const size_t rb = ((size_t)(blkrow + t * 16 + row) * HEADS + h) * DSTATE;
      const int gc = (lane ^ (row & 7)) * 4;
      const f32x4 vr = *(const f32x4*)&Sb[bcur][0][row][lane * 4];
      const f32x4 vi = *(const f32x4*)&Sb[bcur][1][row][lane * 4];
      *(f32x4*)(nsre + rb + gc) = vr;
      *(f32x4*)(nsim + rb + gc) = vi;
    }

    // ---- phase 2b: GEMM2 p-tile [16w,16w+16), K=256 ----
    f32x4 a2 = {0.f,0.f,0.f,0.f};
    #pragma unroll
    for (int j = 0; j < 8; ++j) {
      const short8v pbr = *(const short8v*)&pf[0][j][lane][0];
      const short8v pbi = *(const short8v*)&pf[1][j][lane][0];
      a2 = __builtin_amdgcn_mfma_f32_16x16x32_bf16(w2r[j], pbr, a2, 0, 0, 0);
      a2 = __builtin_amdgcn_mfma_f32_16x16x32_bf16(w2i[j], pbi, a2, 0, 0, 0);
    }

    // ---- epilogue: out = x_t + 2*Ch + D*x_hat (x_t/x_hat from LDS) ----
    {
      const int col = h * HEAD_DIM + w * 16 + g * 4;
      const size_t o = (size_t)(blkrow + t * 16 + bl) * DIM + col;
      const f32x4 xt4 = *(const f32x4*)&xtl[bcur][bl][w * 16 + g * 4];
      const ushort4v xh4 = *(const ushort4v*)&xbl[bcur][bl][w * 16 + g * 4];
      f32x4 ro;
      #pragma unroll
      for (int r = 0; r < 4; ++r)
        ro[r] = xt4[r] + 2.0f * a2[r] + d4[r] * bf2f(xh4[r]);
      *(f32x4*)(out + o) = ro;
    }
    bcur = bnxt;
  }
}

extern "C" void kernel_launch(void* const* d_in, const int* in_sizes, int n_in,
                              void* d_out, int out_size, void* d_ws, size_t ws_size,
                              hipStream_t stream) {
  const float* x_t      = (const float*)d_in[0];
  const float* state_re = (const float*)d_in[1];
  const float* state_im = (const float*)d_in[2];
  const float* norm_w   = (const float*)d_in[3];
  const float* A_re_log = (const float*)d_in[4];
  const float* A_im     = (const float*)d_in[5];
  const float* B_re     = (const float*)d_in[6];
  const float* B_im     = (const float*)d_in[7];
  const float* C_re     = (const float*)d_in[8];
  const float* C_im     = (const float*)d_in[9];
  const float* Dv       = (const float*)d_in[10];
  const float* log_dt   = (const float*)d_in[11];

  float* out   = (float*)d_out;
  float* ns_re = out + (size_t)BATCH * DIM;
  float* ns_im = ns_re + (size_t)BATCH * HEADS * DSTATE;

  char* ws = (char*)d_ws;
  unsigned short* xbf  = (unsigned short*)ws;                       // 16 MB
  unsigned short* w1re = (unsigned short*)(ws + 16777216);          // 512 KB each
  unsigned short* w1im = w1re + 262144;
  unsigned short* w2re = w1im + 262144;
  unsigned short* w2mi = w2re + 262144;
  float* abr = (float*)(ws + 16777216 + 4 * 524288);
  float* abi = abr + 2048;
  float* cre = abi + 2048;
  float* cim = cre + 2048;

  pc_params<<<8, 256, 0, stream>>>(log_dt, A_re_log, A_im, abr, abi, cre, cim);
  pc_w1<<<1024, 256, 0, stream>>>(B_re, B_im, cre, cim, w1re, w1im);
  pc_w2<<<1024, 256, 0, stream>>>(C_re, C_im, w2re, w2mi);
  rms_k<<<2048, 256, 0, stream>>>(x_t, norm_w, xbf);
  s5_main<<<256, 512, 0, stream>>>(xbf, w1re, w1im, w2re, w2mi, abr, abi,
                                   state_re, state_im, x_t, Dv, out, ns_re, ns_im);
}

// Round 10
// 92.301 us; speedup vs baseline: 2.2266x; 1.0951x over previous
//
#include <hip/hip_runtime.h>

#define BATCH 8192
#define DIM 1024
#define HEADS 8
#define HEAD_DIM 128
#define DSTATE 256

typedef __attribute__((ext_vector_type(8))) short short8v;   // 8 bf16 (4 VGPRs)
typedef __attribute__((ext_vector_type(4))) float f32x4;
typedef __attribute__((ext_vector_type(4))) unsigned short ushort4v;
typedef __attribute__((ext_vector_type(4))) unsigned int uint4v;

__device__ __forceinline__ unsigned short f2bf(float x) {
  unsigned int u = __builtin_bit_cast(unsigned int, x);
  unsigned int r = u + 0x7FFFu + ((u >> 16) & 1u);   // RNE
  return (unsigned short)(r >> 16);
}
__device__ __forceinline__ float bf2f(unsigned short h) {
  unsigned int u = ((unsigned int)h) << 16;
  return __builtin_bit_cast(float, u);
}

// async global->LDS: dest = uniform LDS base + lane*size; source is PER-LANE.
__device__ __forceinline__ void stage16f(const float* g, float* l) {
  __builtin_amdgcn_global_load_lds(
      (const __attribute__((address_space(1))) unsigned int*)g,
      (__attribute__((address_space(3))) unsigned int*)l, 16, 0, 0);
}
__device__ __forceinline__ void stage4f(const float* g, float* l) {
  __builtin_amdgcn_global_load_lds(
      (const __attribute__((address_space(1))) unsigned int*)g,
      (__attribute__((address_space(3))) unsigned int*)l, 4, 0, 0);
}

#define BARRIER() do { \
  asm volatile("s_waitcnt lgkmcnt(0)" ::: "memory"); \
  __builtin_amdgcn_s_barrier(); \
  asm volatile("" ::: "memory"); } while (0)

// Row permutation (within each head): stored row s <-> true n.
//   s = 32j + 16t + 4g + r   <->   n = 32j + 8g + 4t + r
// GEMM1's MFMA output (rows s) lands exactly in GEMM2's B-operand layout.

// ---------- prep: W1 (wn-folded, permuted) + A_bar + W2 + row scales ----------
// blocks 0..1023: W1 gen (inline discretization transcendentals)
// blocks 1024..2047: W2 convert
// blocks 2048..4095: RMS row scale (4 rows per block, 1 wave per row)
__global__ __launch_bounds__(256) void prep(
    const float* __restrict__ logdt, const float* __restrict__ arelog,
    const float* __restrict__ aim,
    const float* __restrict__ Bre, const float* __restrict__ Bim,
    const float* __restrict__ Cre, const float* __restrict__ Cim,
    const float* __restrict__ xtg, const float* __restrict__ normw,
    unsigned short* __restrict__ w1re, unsigned short* __restrict__ w1im,
    unsigned short* __restrict__ w2re, unsigned short* __restrict__ w2mi,
    float* __restrict__ abr, float* __restrict__ abi,
    float* __restrict__ scale) {
  const int blk = blockIdx.x;
  if (blk < 1024) {
    const int i = blk * 256 + threadIdx.x;           // h*32768 + s*128 + p
    const int p = i & 127, s = (i >> 7) & 255, h = i >> 15;
    const int kk = s >> 4, u = s & 15;
    const int n = ((kk >> 1) << 5) + ((u >> 2) & 3) * 8 + (kk & 1) * 4 + (u & 3);
    const int hn = h * 256 + n;
    const float ld = logdt[hn];
    const float dt = log1pf(expf(ld));               // softplus
    const float Ar = -expf(arelog[hn]);
    const float Ai = aim[hn];
    const float e = expf(dt * Ar), th = dt * Ai;
    const float Abr = e * cosf(th), Abi = e * sinf(th);
    if (p == 0) { abr[h * 256 + s] = Abr; abi[h * 256 + s] = Abi; }
    const float den = Ar * Ar + Ai * Ai;
    const float br_ = Abr - 1.0f;
    const float cr = (br_ * Ar + Abi * Ai) / den;
    const float ci = (Abi * Ar - br_ * Ai) / den;
    const int src = hn * 128 + p;
    const float wb = normw[h * 128 + p];             // fold norm weight into W1
    const float bre = Bre[src], bim = Bim[src];
    w1re[i] = f2bf((cr * bre - ci * bim) * wb);
    w1im[i] = f2bf((cr * bim + ci * bre) * wb);
  } else if (blk < 2048) {
    const int i = (blk - 1024) * 256 + threadIdx.x;  // 262144 = H*P*N
    w2re[i] = f2bf(Cre[i]);
    w2mi[i] = f2bf(-Cim[i]);
  } else {
    const int wid = threadIdx.x >> 6, lane = threadIdx.x & 63;
    const int row = (blk - 2048) * 4 + wid;
    const float* xr = xtg + (size_t)row * DIM;
    float ssq = 0.f;
    #pragma unroll
    for (int c = 0; c < 4; ++c) {
      const f32x4 v = *(const f32x4*)(xr + c * 256 + lane * 4);
      ssq += v[0]*v[0] + v[1]*v[1] + v[2]*v[2] + v[3]*v[3];
    }
    #pragma unroll
    for (int m = 1; m < 64; m <<= 1) ssq += __shfl_xor(ssq, m, 64);
    if (lane == 0) scale[row] = rsqrtf(ssq * (1.0f / DIM) + 1e-4f);
  }
}

// ---------- main: persistent block, reg weights, 3-buf 2-deep vmcnt pipeline ----------
// Grid: 256 blocks = 32 row-groups x 8 heads (1 block/CU), 512 threads = 8 waves.
// Block: 256 rows x 1 head = 16 tiles of 16 rows. Wave w: GEMM1 n-window j=w,
// GEMM2 p-tile [16w,16w+16). Iter t: vmcnt(K) -> BARRIER -> STAGE(t+2) ->
// phase1(t) -> BARRIER -> phase2(t). STAGE = 6 uniform instrs/wave; two tiles
// of loads stay in flight across barriers (K=6 for t<2, K=10 after).
__global__ __launch_bounds__(512, 2) void s5_main(
    const unsigned short* __restrict__ w1re, const unsigned short* __restrict__ w1im,
    const unsigned short* __restrict__ w2re, const unsigned short* __restrict__ w2mi,
    const float* __restrict__ abrp, const float* __restrict__ abip,
    const float* __restrict__ scale,
    const float* __restrict__ sre, const float* __restrict__ sim,
    const float* __restrict__ xt, const float* __restrict__ dvec,
    const float* __restrict__ normw,
    float* __restrict__ out, float* __restrict__ nsre, float* __restrict__ nsim) {
  __shared__ float Sb[3][2][16][256];                // 96 KB state/ns tiles
  __shared__ float xtl[3][16][128];                  // 24 KB x_t tiles (swizzled)
  __shared__ unsigned short pf[2][8][64][8];         // 16 KB P exchange
  __shared__ float scL[3][64];                       // 768 B row scales
  const int tid = threadIdx.x;
  const int w = tid >> 6, lane = tid & 63;
  const int g = lane >> 4, bl = lane & 15;
  const int h = blockIdx.x & 7;
  const int blkrow = (blockIdx.x >> 3) * 256;

  // ---- persistent weights -> registers (once per block) ----
  short8v w1r[2][4], w1i[2][4];
  #pragma unroll
  for (int t = 0; t < 2; ++t) {
    const int kk = 2 * w + t;
    const unsigned short* pr = w1re + ((size_t)(h * DSTATE + kk * 16 + bl)) * HEAD_DIM + g * 8;
    const unsigned short* pi = w1im + ((size_t)(h * DSTATE + kk * 16 + bl)) * HEAD_DIM + g * 8;
    #pragma unroll
    for (int ks = 0; ks < 4; ++ks) {
      w1r[t][ks] = *(const short8v*)(pr + ks * 32);
      w1i[t][ks] = *(const short8v*)(pi + ks * 32);
    }
  }
  short8v w2r[8], w2i[8];
  {
    const unsigned short* qr = w2re + ((size_t)(h * HEAD_DIM + w * 16 + bl)) * DSTATE + g * 8;
    const unsigned short* qi = w2mi + ((size_t)(h * HEAD_DIM + w * 16 + bl)) * DSTATE + g * 8;
    #pragma unroll
    for (int j = 0; j < 8; ++j) {
      w2r[j] = *(const short8v*)(qr + j * 32);
      w2i[j] = *(const short8v*)(qi + j * 32);
    }
  }
  f32x4 Arh[2], Aih[2];
  #pragma unroll
  for (int t = 0; t < 2; ++t) {
    Arh[t] = *(const f32x4*)(abrp + h * DSTATE + (2 * w + t) * 16 + g * 4);
    Aih[t] = *(const f32x4*)(abip + h * DSTATE + (2 * w + t) * 16 + g * 4);
  }
  f32x4 d4;                                          // D * norm_weight (folded)
  {
    const int col = h * HEAD_DIM + w * 16 + g * 4;
    const f32x4 dv = *(const f32x4*)(dvec + col);
    const f32x4 nv = *(const f32x4*)(normw + col);
    #pragma unroll
    for (int r = 0; r < 4; ++r) d4[r] = dv[r] * nv[r];
  }

  // ---- STAGE tile t into buffer b3: 6 uniform instrs per wave ----
  auto STAGE = [&](int t, int b3) {
    const int gr0 = blkrow + t * 16;
    #pragma unroll
    for (int i = 0; i < 2; ++i) {
      const int row = 2 * w + i;
      const size_t rb = ((size_t)(gr0 + row) * HEADS + h) * DSTATE;
      const int soff = (lane ^ (row & 7)) * 4;       // pre-swizzled source chunk
      stage16f(sre + rb + soff, &Sb[b3][0][row][0]);
      stage16f(sim + rb + soff, &Sb[b3][1][row][0]);
    }
    {
      const int row = 2 * w + (lane >> 5);           // x_t: 2 rows per instr
      const int soff = ((lane & 31) ^ (row & 7)) * 4;
      const float* src = xt + (size_t)(gr0 + row) * DIM + h * HEAD_DIM + soff;
      stage16f(src, &xtl[b3][2 * w][0]);
    }
    stage4f(scale + gr0 + (lane & 15), &scL[b3][0]);
  };

  STAGE(0, 0);
  STAGE(1, 1);

  for (int t = 0; t < 16; ++t) {
    const int bcur = t % 3;
    if (t < 2) { asm volatile("s_waitcnt vmcnt(6)"  ::: "memory"); }
    else       { asm volatile("s_waitcnt vmcnt(10)" ::: "memory"); }
    BARRIER();                                       // stage(t) visible to all

    if (t + 2 < 16) STAGE(t + 2, (t + 2) % 3);

    // ---- phase 1: x_hat frags from LDS, GEMM1 + recurrence on n-window j=w ----
    const float scl = scL[bcur][bl];
    short8v xf[4];
    #pragma unroll
    for (int ks = 0; ks < 4; ++ks) {
      const f32x4 x0 = *(const f32x4*)&xtl[bcur][bl][(((ks * 8 + 2 * g)     ^ (bl & 7)) << 2)];
      const f32x4 x1 = *(const f32x4*)&xtl[bcur][bl][(((ks * 8 + 2 * g + 1) ^ (bl & 7)) << 2)];
      uint4v uv;
      uv[0] = (unsigned)f2bf(x0[0] * scl) | ((unsigned)f2bf(x0[1] * scl) << 16);
      uv[1] = (unsigned)f2bf(x0[2] * scl) | ((unsigned)f2bf(x0[3] * scl) << 16);
      uv[2] = (unsigned)f2bf(x1[0] * scl) | ((unsigned)f2bf(x1[1] * scl) << 16);
      uv[3] = (unsigned)f2bf(x1[2] * scl) | ((unsigned)f2bf(x1[3] * scl) << 16);
      xf[ks] = __builtin_bit_cast(short8v, uv);
    }

    unsigned pr0 = 0, pr1 = 0, pi0 = 0, pi1 = 0;
    #pragma unroll
    for (int tt = 0; tt < 2; ++tt) {
      f32x4 dr = {0.f,0.f,0.f,0.f};
      f32x4 di = {0.f,0.f,0.f,0.f};
      #pragma unroll
      for (int ks = 0; ks < 4; ++ks)
        dr = __builtin_amdgcn_mfma_f32_16x16x32_bf16(w1r[tt][ks], xf[ks], dr, 0, 0, 0);
      #pragma unroll
      for (int ks = 0; ks < 4; ++ks)
        di = __builtin_amdgcn_mfma_f32_16x16x32_bf16(w1i[tt][ks], xf[ks], di, 0, 0, 0);
      const int c = (((8 * w + 2 * g + tt) ^ (bl & 7)) << 2);
      const f32x4 s_r = *(const f32x4*)&Sb[bcur][0][bl][c];
      const f32x4 s_i = *(const f32x4*)&Sb[bcur][1][bl][c];
      f32x4 nr, ni;
      #pragma unroll
      for (int r = 0; r < 4; ++r) {
        nr[r] = fmaf(Arh[tt][r], s_r[r], fmaf(-Aih[tt][r], s_i[r], dr[r]));
        ni[r] = fmaf(Arh[tt][r], s_i[r], fmaf(Aih[tt][r], s_r[r], di[r]));
      }
      *(f32x4*)&Sb[bcur][0][bl][c] = nr;
      *(f32x4*)&Sb[bcur][1][bl][c] = ni;
      unsigned lo  = (unsigned)f2bf(nr[0]) | ((unsigned)f2bf(nr[1]) << 16);
      unsigned hi  = (unsigned)f2bf(nr[2]) | ((unsigned)f2bf(nr[3]) << 16);
      unsigned lo2 = (unsigned)f2bf(ni[0]) | ((unsigned)f2bf(ni[1]) << 16);
      unsigned hi2 = (unsigned)f2bf(ni[2]) | ((unsigned)f2bf(ni[3]) << 16);
      if (tt == 0) { pr0 = lo; pr1 = hi; pi0 = lo2; pi1 = hi2; }
      else {
        uint4v urv; urv[0] = pr0; urv[1] = pr1; urv[2] = lo;  urv[3] = hi;
        uint4v uiv; uiv[0] = pi0; uiv[1] = pi1; uiv[2] = lo2; uiv[3] = hi2;
        *(short8v*)&pf[0][w][lane][0] = __builtin_bit_cast(short8v, urv);
        *(short8v*)&pf[1][w][lane][0] = __builtin_bit_cast(short8v, uiv);
      }
    }
    BARRIER();                                       // ns + P complete

    // ---- phase 2a: contiguous ns store-out (rows 2w, 2w+1) ----
    #pragma unroll
    for (int i = 0; i < 2; ++i) {
      const int row = 2 * w + i;
      const size_t rb = ((size_t)(blkrow + t * 16 + row) * HEADS + h) * DSTATE;
      const int gc = (lane ^ (row & 7)) * 4;
      const f32x4 vr = *(const f32x4*)&Sb[bcur][0][row][lane * 4];
      const f32x4 vi = *(const f32x4*)&Sb[bcur][1][row][lane * 4];
      *(f32x4*)(nsre + rb + gc) = vr;
      *(f32x4*)(nsim + rb + gc) = vi;
    }

    // ---- phase 2b: GEMM2 p-tile [16w,16w+16), K=256 ----
    f32x4 a2 = {0.f,0.f,0.f,0.f};
    #pragma unroll
    for (int j = 0; j < 8; ++j) {
      const short8v pbr = *(const short8v*)&pf[0][j][lane][0];
      const short8v pbi = *(const short8v*)&pf[1][j][lane][0];
      a2 = __builtin_amdgcn_mfma_f32_16x16x32_bf16(w2r[j], pbr, a2, 0, 0, 0);
      a2 = __builtin_amdgcn_mfma_f32_16x16x32_bf16(w2i[j], pbi, a2, 0, 0, 0);
    }

    // ---- epilogue: out = x_t + 2*Ch + (D*wn)*scale*x_t ----
    {
      const int col = h * HEAD_DIM + w * 16 + g * 4;
      const size_t o = (size_t)(blkrow + t * 16 + bl) * DIM + col;
      const f32x4 xt4 = *(const f32x4*)&xtl[bcur][bl][(((4 * w + g) ^ (bl & 7)) << 2)];
      f32x4 ro;
      #pragma unroll
      for (int r = 0; r < 4; ++r)
        ro[r] = xt4[r] * (1.0f + d4[r] * scl) + 2.0f * a2[r];
      *(f32x4*)(out + o) = ro;
    }
  }
}

extern "C" void kernel_launch(void* const* d_in, const int* in_sizes, int n_in,
                              void* d_out, int out_size, void* d_ws, size_t ws_size,
                              hipStream_t stream) {
  const float* x_t      = (const float*)d_in[0];
  const float* state_re = (const float*)d_in[1];
  const float* state_im = (const float*)d_in[2];
  const float* norm_w   = (const float*)d_in[3];
  const float* A_re_log = (const float*)d_in[4];
  const float* A_im     = (const float*)d_in[5];
  const float* B_re     = (const float*)d_in[6];
  const float* B_im     = (const float*)d_in[7];
  const float* C_re     = (const float*)d_in[8];
  const float* C_im     = (const float*)d_in[9];
  const float* Dv       = (const float*)d_in[10];
  const float* log_dt   = (const float*)d_in[11];

  float* out   = (float*)d_out;
  float* ns_re = out + (size_t)BATCH * DIM;
  float* ns_im = ns_re + (size_t)BATCH * HEADS * DSTATE;

  char* ws = (char*)d_ws;
  unsigned short* w1re = (unsigned short*)ws;                       // 512 KB each
  unsigned short* w1im = w1re + 262144;
  unsigned short* w2re = w1im + 262144;
  unsigned short* w2mi = w2re + 262144;
  float* abr   = (float*)(ws + 4 * 524288);
  float* abi   = abr + 2048;
  float* scale = abi + 2048;                                        // 8192 f32

  prep<<<4096, 256, 0, stream>>>(log_dt, A_re_log, A_im, B_re, B_im, C_re, C_im,
                                 x_t, norm_w, w1re, w1im, w2re, w2mi,
                                 abr, abi, scale);
  s5_main<<<256, 512, 0, stream>>>(w1re, w1im, w2re, w2mi, abr, abi, scale,
                                   state_re, state_im, x_t, Dv, norm_w,
                                   out, ns_re, ns_im);
}